// Round 4
// baseline (157.825 us; speedup 1.0000x reference)
//
#include <hip/hip_runtime.h>
#include <hip/hip_bf16.h>

// Problem dims (AdditiveAttention_56865366999388)
#define NB 4
#define NQL 512   // query length
#define ML 512    // key/value length
#define DDIM 256  // DQ == DK == DV
#define HDIM 256  // H
#define PSZ ((size_t)NB * NQL * ML)   // one partial-S buffer (element count)

static constexpr float TWO_LOG2E = 2.8853900817779268f; // 2*log2(e)
static constexpr float LOG2E     = 1.4426950408889634f;

// ---------------------------------------------------------------------------
// Kernel 1: projection + exp.  (unchanged from R3)
//   EqT[b][h][l] = exp2( TWO_LOG2E * sum_d q_src[b][l][d]*Wq[d][h] )  (= e^{2q})
// grid: (16, 4, 8). block 256. 32l x 64h tile, 2l x 4h per thread.
// ---------------------------------------------------------------------------
__global__ __launch_bounds__(256) void proj_kernel(
    const float* __restrict__ q_src, const float* __restrict__ k_src,
    const float* __restrict__ Wq,    const float* __restrict__ Wk,
    float* __restrict__ EqT,         float* __restrict__ EkT)
{
    const int z = blockIdx.z;
    const int b = z & 3;
    const int which = z >> 2;
    const float* __restrict__ src  = which ? k_src : q_src;
    const float* __restrict__ W    = which ? Wk    : Wq;
    float* __restrict__       outT = which ? EkT   : EqT;

    const int l0 = blockIdx.x * 32;
    const int h0 = blockIdx.y * 64;
    const int t  = threadIdx.x;
    const int tx = t & 15;   // h group (4 each)
    const int ty = t >> 4;   // l (2 each)

    __shared__ __align__(16) float sX[32][36];   // [dd][ll]
    __shared__ __align__(16) float sW[32][68];   // [dd][hh]

    float acc[2][4];
    #pragma unroll
    for (int i = 0; i < 2; i++)
        #pragma unroll
        for (int j = 0; j < 4; j++) acc[i][j] = 0.f;

    const int llA = t >> 3, dgA = t & 7;   // X: 32 l rows x 8 d-groups(4)
    const int ddB = t >> 3, hgB = t & 7;   // W: 32 d rows x 8 h-groups(8)

    for (int d0 = 0; d0 < DDIM; d0 += 32) {
        float4 xv = *(const float4*)&src[(size_t)(b * NQL + l0 + llA) * DDIM + d0 + dgA * 4];
        const float* wrow = &W[(size_t)(d0 + ddB) * HDIM + h0 + hgB * 8];
        float4 wa = ((const float4*)wrow)[0];
        float4 wb = ((const float4*)wrow)[1];
        __syncthreads();
        sX[dgA * 4 + 0][llA] = xv.x;
        sX[dgA * 4 + 1][llA] = xv.y;
        sX[dgA * 4 + 2][llA] = xv.z;
        sX[dgA * 4 + 3][llA] = xv.w;
        *(float4*)&sW[ddB][hgB * 8]     = wa;
        *(float4*)&sW[ddB][hgB * 8 + 4] = wb;
        __syncthreads();
        #pragma unroll
        for (int dd = 0; dd < 32; dd++) {
            float4 w4 = *(const float4*)&sW[dd][tx * 4];
            float2 x2 = *(const float2*)&sX[dd][ty * 2];
            acc[0][0] = fmaf(x2.x, w4.x, acc[0][0]);
            acc[0][1] = fmaf(x2.x, w4.y, acc[0][1]);
            acc[0][2] = fmaf(x2.x, w4.z, acc[0][2]);
            acc[0][3] = fmaf(x2.x, w4.w, acc[0][3]);
            acc[1][0] = fmaf(x2.y, w4.x, acc[1][0]);
            acc[1][1] = fmaf(x2.y, w4.y, acc[1][1]);
            acc[1][2] = fmaf(x2.y, w4.z, acc[1][2]);
            acc[1][3] = fmaf(x2.y, w4.w, acc[1][3]);
        }
    }

    #pragma unroll
    for (int j = 0; j < 4; j++) {
        float2 o;
        o.x = __builtin_amdgcn_exp2f(acc[0][j] * TWO_LOG2E);
        o.y = __builtin_amdgcn_exp2f(acc[1][j] * TWO_LOG2E);
        *(float2*)&outT[(size_t)(b * HDIM + h0 + tx * 4 + j) * NQL + l0 + ty * 2] = o;
    }
}

// ---------------------------------------------------------------------------
// Kernel 2 (v4): partial scores with h-split.
//   Sp[p][b][n][m] = sum_{h in [64p,64p+64)} ( Wv[h] - 2*Wv[h]/(Eq*Ek+1) )
// grid: (8 m-tiles, 8 n-tiles, 16 = b + 4*p) = 1024 blocks (4/CU). block 256.
// 64n x 64m tile, 4n x 4m per thread (2 B LDS / element).
// One-shot staging: whole 64h x 64n Q-slab + 64h x 64m K-slab in LDS,
// exactly two barriers, then 64 pure-VALU iterations.
// ---------------------------------------------------------------------------
__global__ __launch_bounds__(256) void scores_kernel(
    const float* __restrict__ EqT, const float* __restrict__ EkT,
    const float* __restrict__ Wv, float* __restrict__ Sp)
{
    const int z  = blockIdx.z;
    const int b  = z & 3;
    const int p  = z >> 2;        // h-split index 0..3
    const int h0 = p * 64;
    const int m0 = blockIdx.x * 64;
    const int n0 = blockIdx.y * 64;
    const int t  = threadIdx.x;
    const int tx = t & 15;   // m group (4 m)
    const int ty = t >> 4;   // n group (4 n)

    __shared__ __align__(16) float sQ[64][68];   // [hh][nn]
    __shared__ __align__(16) float sK[64][68];   // [hh][mm]
    __shared__ __align__(16) float sWV[64];

    // ---- one-shot staging: hh = t>>2 (0..63), cg = t&3 (16 floats each)
    {
        const int hh = t >> 2, cg = t & 3;
        const float* qsrc = &EqT[(size_t)(b * HDIM + h0 + hh) * NQL + n0 + cg * 16];
        const float* ksrc = &EkT[(size_t)(b * HDIM + h0 + hh) * ML  + m0 + cg * 16];
        float4 q0 = ((const float4*)qsrc)[0];
        float4 q1 = ((const float4*)qsrc)[1];
        float4 q2 = ((const float4*)qsrc)[2];
        float4 q3 = ((const float4*)qsrc)[3];
        float4 k0 = ((const float4*)ksrc)[0];
        float4 k1 = ((const float4*)ksrc)[1];
        float4 k2 = ((const float4*)ksrc)[2];
        float4 k3 = ((const float4*)ksrc)[3];
        *(float4*)&sQ[hh][cg * 16 + 0]  = q0;
        *(float4*)&sQ[hh][cg * 16 + 4]  = q1;
        *(float4*)&sQ[hh][cg * 16 + 8]  = q2;
        *(float4*)&sQ[hh][cg * 16 + 12] = q3;
        *(float4*)&sK[hh][cg * 16 + 0]  = k0;
        *(float4*)&sK[hh][cg * 16 + 4]  = k1;
        *(float4*)&sK[hh][cg * 16 + 8]  = k2;
        *(float4*)&sK[hh][cg * 16 + 12] = k3;
        if (t < 64) sWV[t] = Wv[h0 + t];
    }
    __syncthreads();

    float acc[4][4];
    #pragma unroll
    for (int i = 0; i < 4; i++)
        #pragma unroll
        for (int j = 0; j < 4; j++) acc[i][j] = 0.f;
    float swv = 0.f;

    for (int h4 = 0; h4 < 16; h4++) {
        float4 wv4 = *(const float4*)&sWV[h4 * 4];    // broadcast
        float wvs[4] = {wv4.x, wv4.y, wv4.z, wv4.w};
        #pragma unroll
        for (int u = 0; u < 4; u++) {
            const int hh = h4 * 4 + u;
            float4 q4 = *(const float4*)&sQ[hh][ty * 4];   // 4-addr broadcast
            float4 k4 = *(const float4*)&sK[hh][tx * 4];   // 2-way alias (free)
            const float wv  = wvs[u];
            swv += wv;
            const float nw2 = -2.0f * wv;
            float qs[4] = {q4.x, q4.y, q4.z, q4.w};
            #pragma unroll
            for (int i = 0; i < 4; i++) {
                float a0 = fmaf(qs[i], k4.x, 1.0f);   // e^{2(q+k)} + 1
                float a1 = fmaf(qs[i], k4.y, 1.0f);
                float a2 = fmaf(qs[i], k4.z, 1.0f);
                float a3 = fmaf(qs[i], k4.w, 1.0f);
                float r01 = __builtin_amdgcn_rcpf(a0 * a1);
                float r23 = __builtin_amdgcn_rcpf(a2 * a3);
                acc[i][0] = fmaf(nw2, r01 * a1, acc[i][0]);
                acc[i][1] = fmaf(nw2, r01 * a0, acc[i][1]);
                acc[i][2] = fmaf(nw2, r23 * a3, acc[i][2]);
                acc[i][3] = fmaf(nw2, r23 * a2, acc[i][3]);
            }
        }
    }

    float* srow = &Sp[p * PSZ + (size_t)(b * NQL + n0 + ty * 4) * ML + m0 + tx * 4];
    #pragma unroll
    for (int i = 0; i < 4; i++) {
        float4 o = {swv + acc[i][0], swv + acc[i][1],
                    swv + acc[i][2], swv + acc[i][3]};
        *(float4*)&srow[(size_t)i * ML] = o;
    }
}

// ---------------------------------------------------------------------------
// Kernel 3: fused partial-sum + softmax + AV.
// Phase 1: sum the 4 h-split partials, exp rows into LDS (16n x 512m) + sums.
// (|S| <= sum|Wv| ~ 13 -> no max-subtraction needed.)
// Phase 2: O[n][v] = (1/rowsum) * sum_m P[n][m]*V[m][v], V direct from global.
// grid: (4 v-tiles, 32 n-tiles, 4 b) = 512 blocks. block 256.
// ---------------------------------------------------------------------------
__global__ __launch_bounds__(256) void sav_kernel(
    const float* __restrict__ Sp, const float* __restrict__ V,
    float* __restrict__ O)
{
    const int b  = blockIdx.z;
    const int v0 = blockIdx.x * 64;
    const int n0 = blockIdx.y * 16;
    const int t  = threadIdx.x;

    __shared__ __align__(16) float sP[16][516];
    __shared__ __align__(16) float sRed[16][16];

    // ---- phase 1: partial-sum + exp + partial row sums
    const int row = t >> 4;
    const int seg = t & 15;
    {
        const float* srow = &Sp[(size_t)(b * NQL + n0 + row) * ML + seg * 32];
        float psum = 0.f;
        #pragma unroll
        for (int i = 0; i < 8; i++) {
            float4 s0 = ((const float4*)(srow + 0 * PSZ))[i];
            float4 s1 = ((const float4*)(srow + 1 * PSZ))[i];
            float4 s2 = ((const float4*)(srow + 2 * PSZ))[i];
            float4 s3 = ((const float4*)(srow + 3 * PSZ))[i];
            float4 sv;
            sv.x = (s0.x + s1.x) + (s2.x + s3.x);
            sv.y = (s0.y + s1.y) + (s2.y + s3.y);
            sv.z = (s0.z + s1.z) + (s2.z + s3.z);
            sv.w = (s0.w + s1.w) + (s2.w + s3.w);
            float4 e;
            e.x = __builtin_amdgcn_exp2f(sv.x * LOG2E);
            e.y = __builtin_amdgcn_exp2f(sv.y * LOG2E);
            e.z = __builtin_amdgcn_exp2f(sv.z * LOG2E);
            e.w = __builtin_amdgcn_exp2f(sv.w * LOG2E);
            *(float4*)&sP[row][seg * 32 + i * 4] = e;
            psum += (e.x + e.y) + (e.z + e.w);
        }
        sRed[row][seg] = psum;
    }
    __syncthreads();

    // ---- phase 2: AV.  tx = n (0..15), ty = v-group (0..15)
    const int tx = t & 15;
    const int ty = t >> 4;
    float rs = 0.f;
    #pragma unroll
    for (int i = 0; i < 16; i++) rs += sRed[tx][i];   // broadcast reads
    const float inv = 1.0f / rs;

    float4 acc = {0.f, 0.f, 0.f, 0.f};
    const float* vbase = &V[(size_t)b * ML * DDIM + v0 + ty * 4];
    #pragma unroll 2
    for (int m4 = 0; m4 < 128; m4++) {
        float4 a4 = *(const float4*)&sP[tx][m4 * 4];    // 2-way bank alias
        float4 va = *(const float4*)&vbase[(size_t)(m4 * 4 + 0) * DDIM];
        float4 vb = *(const float4*)&vbase[(size_t)(m4 * 4 + 1) * DDIM];
        float4 vc = *(const float4*)&vbase[(size_t)(m4 * 4 + 2) * DDIM];
        float4 vd = *(const float4*)&vbase[(size_t)(m4 * 4 + 3) * DDIM];
        acc.x = fmaf(a4.x, va.x, acc.x);
        acc.y = fmaf(a4.x, va.y, acc.y);
        acc.z = fmaf(a4.x, va.z, acc.z);
        acc.w = fmaf(a4.x, va.w, acc.w);
        acc.x = fmaf(a4.y, vb.x, acc.x);
        acc.y = fmaf(a4.y, vb.y, acc.y);
        acc.z = fmaf(a4.y, vb.z, acc.z);
        acc.w = fmaf(a4.y, vb.w, acc.w);
        acc.x = fmaf(a4.z, vc.x, acc.x);
        acc.y = fmaf(a4.z, vc.y, acc.y);
        acc.z = fmaf(a4.z, vc.z, acc.z);
        acc.w = fmaf(a4.z, vc.w, acc.w);
        acc.x = fmaf(a4.w, vd.x, acc.x);
        acc.y = fmaf(a4.w, vd.y, acc.y);
        acc.z = fmaf(a4.w, vd.z, acc.z);
        acc.w = fmaf(a4.w, vd.w, acc.w);
    }

    float4 o;
    o.x = acc.x * inv; o.y = acc.y * inv; o.z = acc.z * inv; o.w = acc.w * inv;
    *(float4*)&O[(size_t)(b * NQL + n0 + tx) * DDIM + v0 + ty * 4] = o;
}

// ---------------------------------------------------------------------------
extern "C" void kernel_launch(void* const* d_in, const int* in_sizes, int n_in,
                              void* d_out, int out_size, void* d_ws, size_t ws_size,
                              hipStream_t stream)
{
    const float* query = (const float*)d_in[0]; // (4,512,256)
    const float* key   = (const float*)d_in[1]; // (4,512,256)
    const float* value = (const float*)d_in[2]; // (4,512,256)
    const float* Wq    = (const float*)d_in[3]; // (256,256)
    const float* Wk    = (const float*)d_in[4]; // (256,256)
    const float* Wv    = (const float*)d_in[5]; // (256,)
    float* out = (float*)d_out;                 // (4,512,256)

    // workspace layout (fp32): EqT 2MB | EkT 2MB | Sp 4 x 4MB = 20 MB total
    float* EqT = (float*)d_ws;                        // [4][256][512]
    float* EkT = EqT + (size_t)NB * HDIM * NQL;       // [4][256][512]
    float* Sp  = EkT + (size_t)NB * HDIM * ML;        // [4][4][512][512]

    dim3 gProj(NQL / 32, HDIM / 64, NB * 2);
    proj_kernel<<<gProj, 256, 0, stream>>>(query, key, Wq, Wk, EqT, EkT);

    dim3 gSc(ML / 64, NQL / 64, NB * 4);
    scores_kernel<<<gSc, 256, 0, stream>>>(EqT, EkT, Wv, Sp);

    dim3 gSav(DDIM / 64, NQL / 16, NB);
    sav_kernel<<<gSav, 256, 0, stream>>>(Sp, value, out);
}

// Round 5
// 143.763 us; speedup vs baseline: 1.0978x; 1.0978x over previous
//
#include <hip/hip_runtime.h>
#include <hip/hip_bf16.h>

// Problem dims (AdditiveAttention_56865366999388)
#define NB 4
#define NQL 512   // query length
#define ML 512    // key/value length
#define DDIM 256  // DQ == DK == DV
#define HDIM 256  // H

static constexpr float TWO_LOG2E = 2.8853900817779268f; // 2*log2(e)
static constexpr float LOG2E     = 1.4426950408889634f;

typedef float v2f __attribute__((ext_vector_type(2)));

// ---------------------------------------------------------------------------
// Kernel 1: projection + exp.  (unchanged)
//   EqT[b][h][l] = exp2( TWO_LOG2E * sum_d q_src[b][l][d]*Wq[d][h] )  (= e^{2q})
// grid: (16, 4, 8). block 256. 32l x 64h tile, 2l x 4h per thread.
// ---------------------------------------------------------------------------
__global__ __launch_bounds__(256) void proj_kernel(
    const float* __restrict__ q_src, const float* __restrict__ k_src,
    const float* __restrict__ Wq,    const float* __restrict__ Wk,
    float* __restrict__ EqT,         float* __restrict__ EkT)
{
    const int z = blockIdx.z;
    const int b = z & 3;
    const int which = z >> 2;
    const float* __restrict__ src  = which ? k_src : q_src;
    const float* __restrict__ W    = which ? Wk    : Wq;
    float* __restrict__       outT = which ? EkT   : EqT;

    const int l0 = blockIdx.x * 32;
    const int h0 = blockIdx.y * 64;
    const int t  = threadIdx.x;
    const int tx = t & 15;   // h group (4 each)
    const int ty = t >> 4;   // l (2 each)

    __shared__ __align__(16) float sX[32][36];   // [dd][ll]
    __shared__ __align__(16) float sW[32][68];   // [dd][hh]

    float acc[2][4];
    #pragma unroll
    for (int i = 0; i < 2; i++)
        #pragma unroll
        for (int j = 0; j < 4; j++) acc[i][j] = 0.f;

    const int llA = t >> 3, dgA = t & 7;   // X: 32 l rows x 8 d-groups(4)
    const int ddB = t >> 3, hgB = t & 7;   // W: 32 d rows x 8 h-groups(8)

    for (int d0 = 0; d0 < DDIM; d0 += 32) {
        float4 xv = *(const float4*)&src[(size_t)(b * NQL + l0 + llA) * DDIM + d0 + dgA * 4];
        const float* wrow = &W[(size_t)(d0 + ddB) * HDIM + h0 + hgB * 8];
        float4 wa = ((const float4*)wrow)[0];
        float4 wb = ((const float4*)wrow)[1];
        __syncthreads();
        sX[dgA * 4 + 0][llA] = xv.x;
        sX[dgA * 4 + 1][llA] = xv.y;
        sX[dgA * 4 + 2][llA] = xv.z;
        sX[dgA * 4 + 3][llA] = xv.w;
        *(float4*)&sW[ddB][hgB * 8]     = wa;
        *(float4*)&sW[ddB][hgB * 8 + 4] = wb;
        __syncthreads();
        #pragma unroll
        for (int dd = 0; dd < 32; dd++) {
            float4 w4 = *(const float4*)&sW[dd][tx * 4];
            float2 x2 = *(const float2*)&sX[dd][ty * 2];
            acc[0][0] = fmaf(x2.x, w4.x, acc[0][0]);
            acc[0][1] = fmaf(x2.x, w4.y, acc[0][1]);
            acc[0][2] = fmaf(x2.x, w4.z, acc[0][2]);
            acc[0][3] = fmaf(x2.x, w4.w, acc[0][3]);
            acc[1][0] = fmaf(x2.y, w4.x, acc[1][0]);
            acc[1][1] = fmaf(x2.y, w4.y, acc[1][1]);
            acc[1][2] = fmaf(x2.y, w4.z, acc[1][2]);
            acc[1][3] = fmaf(x2.y, w4.w, acc[1][3]);
        }
    }

    #pragma unroll
    for (int j = 0; j < 4; j++) {
        float2 o;
        o.x = __builtin_amdgcn_exp2f(acc[0][j] * TWO_LOG2E);
        o.y = __builtin_amdgcn_exp2f(acc[1][j] * TWO_LOG2E);
        *(float2*)&outT[(size_t)(b * HDIM + h0 + tx * 4 + j) * NQL + l0 + ty * 2] = o;
    }
}

// ---------------------------------------------------------------------------
// Kernel 2 (v5): full-h scores, epilogue-fused exp.
//   S[n][m] = sum_h ( Wv[h] - 2*Wv[h]/(Eq*Ek+1) );   P = e^S  (no max needed,
//   |S| <= sum|Wv| ~ 13).
// grid: (8 m-tiles, 16 n-tiles, 4 b) = 512 blocks (2/CU). block 256.
// 32n x 64m tile, 2n x 4m per thread; math packed as float2 over the n-pair
// (targets v_pk_fma_f32/v_pk_mul_f32). 3 B LDS / element.
// ---------------------------------------------------------------------------
__global__ __launch_bounds__(256) void scores_kernel(
    const float* __restrict__ EqT, const float* __restrict__ EkT,
    const float* __restrict__ Wv, float* __restrict__ P)
{
    const int b  = blockIdx.z;
    const int m0 = blockIdx.x * 64;
    const int n0 = blockIdx.y * 32;
    const int t  = threadIdx.x;
    const int tx = t & 15;   // m group (4 m)
    const int ty = t >> 4;   // n pair (rows 2ty, 2ty+1)

    __shared__ __align__(16) float sQ[32][36];   // [hh][nn]
    __shared__ __align__(16) float sK[32][68];   // [hh][mm]
    __shared__ __align__(16) float sWV[32];

    v2f acc0 = {0.f, 0.f}, acc1 = {0.f, 0.f};
    v2f acc2 = {0.f, 0.f}, acc3 = {0.f, 0.f};
    float swv = 0.f;

    const int hhA = t >> 3, cgA = t & 7;

    for (int h0 = 0; h0 < HDIM; h0 += 32) {
        float4 qv = *(const float4*)&EqT[(size_t)(b * HDIM + h0 + hhA) * NQL + n0 + cgA * 4];
        const float* krow = &EkT[(size_t)(b * HDIM + h0 + hhA) * ML + m0 + cgA * 8];
        float4 ka = ((const float4*)krow)[0];
        float4 kb = ((const float4*)krow)[1];
        float wv_ld = (t < 32) ? Wv[h0 + t] : 0.f;
        __syncthreads();
        *(float4*)&sQ[hhA][cgA * 4]     = qv;
        *(float4*)&sK[hhA][cgA * 8]     = ka;
        *(float4*)&sK[hhA][cgA * 8 + 4] = kb;
        if (t < 32) sWV[t] = wv_ld;
        __syncthreads();
        #pragma unroll
        for (int h4 = 0; h4 < 8; h4++) {
            float4 wv4 = *(const float4*)&sWV[h4 * 4];      // broadcast
            float wvs[4] = {wv4.x, wv4.y, wv4.z, wv4.w};
            #pragma unroll
            for (int u = 0; u < 4; u++) {
                const int hh = h4 * 4 + u;
                v2f   q2 = *(const v2f*)&sQ[hh][ty * 2];    // n-pair
                float4 k4 = *(const float4*)&sK[hh][tx * 4];
                const float wv = wvs[u];
                swv += wv;
                const float nw2 = -2.0f * wv;
                // a_j = Eq*Ek_j + 1, packed over the n-pair (fp-contract -> pk_fma)
                v2f a0 = q2 * k4.x + 1.0f;
                v2f a1 = q2 * k4.y + 1.0f;
                v2f a2 = q2 * k4.z + 1.0f;
                v2f a3 = q2 * k4.w + 1.0f;
                v2f p01 = a0 * a1;
                v2f p23 = a2 * a3;
                v2f r01, r23;
                r01.x = __builtin_amdgcn_rcpf(p01.x);
                r01.y = __builtin_amdgcn_rcpf(p01.y);
                r23.x = __builtin_amdgcn_rcpf(p23.x);
                r23.y = __builtin_amdgcn_rcpf(p23.y);
                acc0 += (r01 * a1) * nw2;
                acc1 += (r01 * a0) * nw2;
                acc2 += (r23 * a3) * nw2;
                acc3 += (r23 * a2) * nw2;
            }
        }
    }

    // epilogue: S = swv + acc;  P = e^S = exp2(S * log2 e)
    v2f s0 = acc0 + swv, s1 = acc1 + swv, s2 = acc2 + swv, s3 = acc3 + swv;
    float4 row0, row1;
    row0.x = __builtin_amdgcn_exp2f(s0.x * LOG2E);
    row0.y = __builtin_amdgcn_exp2f(s1.x * LOG2E);
    row0.z = __builtin_amdgcn_exp2f(s2.x * LOG2E);
    row0.w = __builtin_amdgcn_exp2f(s3.x * LOG2E);
    row1.x = __builtin_amdgcn_exp2f(s0.y * LOG2E);
    row1.y = __builtin_amdgcn_exp2f(s1.y * LOG2E);
    row1.z = __builtin_amdgcn_exp2f(s2.y * LOG2E);
    row1.w = __builtin_amdgcn_exp2f(s3.y * LOG2E);
    float* prow = &P[(size_t)(b * NQL + n0 + ty * 2) * ML + m0 + tx * 4];
    *(float4*)&prow[0]  = row0;
    *(float4*)&prow[ML] = row1;
}

// ---------------------------------------------------------------------------
// Kernel 3 (v5): softmax-normalize + AV, P already exponentiated.
// Phase 1: copy 16n x 512m P-slab into LDS + partial row sums.
// Phase 2: O[n][v] = (1/rowsum) * sum_m P[n][m]*V[m][v], V direct from global
// (L2-resident). tx=n, ty=v-group -> 16 n-lanes share one V address.
// grid: (4 v-tiles, 32 n-tiles, 4 b) = 512 blocks. block 256.
// ---------------------------------------------------------------------------
__global__ __launch_bounds__(256) void sav_kernel(
    const float* __restrict__ P, const float* __restrict__ V,
    float* __restrict__ O)
{
    const int b  = blockIdx.z;
    const int v0 = blockIdx.x * 64;
    const int n0 = blockIdx.y * 16;
    const int t  = threadIdx.x;

    __shared__ __align__(16) float sP[16][516];
    __shared__ __align__(16) float sRed[16][16];

    // ---- phase 1: stage P + partial row sums (row = t>>4, seg = t&15)
    const int row = t >> 4;
    const int seg = t & 15;
    {
        const float* prow = &P[(size_t)(b * NQL + n0 + row) * ML + seg * 32];
        float psum = 0.f;
        #pragma unroll
        for (int i = 0; i < 8; i++) {
            float4 e = ((const float4*)prow)[i];
            *(float4*)&sP[row][seg * 32 + i * 4] = e;
            psum += (e.x + e.y) + (e.z + e.w);
        }
        sRed[row][seg] = psum;
    }
    __syncthreads();

    // ---- phase 2: AV.  tx = n (0..15), ty = v-group (0..15)
    const int tx = t & 15;
    const int ty = t >> 4;
    float rs = 0.f;
    #pragma unroll
    for (int i = 0; i < 16; i++) rs += sRed[tx][i];   // broadcast reads
    const float inv = 1.0f / rs;

    float4 acc = {0.f, 0.f, 0.f, 0.f};
    const float* vbase = &V[(size_t)b * ML * DDIM + v0 + ty * 4];
    #pragma unroll 2
    for (int m4 = 0; m4 < 128; m4++) {
        float4 a4 = *(const float4*)&sP[tx][m4 * 4];    // 2-way bank alias
        float4 va = *(const float4*)&vbase[(size_t)(m4 * 4 + 0) * DDIM];
        float4 vb = *(const float4*)&vbase[(size_t)(m4 * 4 + 1) * DDIM];
        float4 vc = *(const float4*)&vbase[(size_t)(m4 * 4 + 2) * DDIM];
        float4 vd = *(const float4*)&vbase[(size_t)(m4 * 4 + 3) * DDIM];
        acc.x = fmaf(a4.x, va.x, acc.x);
        acc.y = fmaf(a4.x, va.y, acc.y);
        acc.z = fmaf(a4.x, va.z, acc.z);
        acc.w = fmaf(a4.x, va.w, acc.w);
        acc.x = fmaf(a4.y, vb.x, acc.x);
        acc.y = fmaf(a4.y, vb.y, acc.y);
        acc.z = fmaf(a4.y, vb.z, acc.z);
        acc.w = fmaf(a4.y, vb.w, acc.w);
        acc.x = fmaf(a4.z, vc.x, acc.x);
        acc.y = fmaf(a4.z, vc.y, acc.y);
        acc.z = fmaf(a4.z, vc.z, acc.z);
        acc.w = fmaf(a4.z, vc.w, acc.w);
        acc.x = fmaf(a4.w, vd.x, acc.x);
        acc.y = fmaf(a4.w, vd.y, acc.y);
        acc.z = fmaf(a4.w, vd.z, acc.z);
        acc.w = fmaf(a4.w, vd.w, acc.w);
    }

    float4 o;
    o.x = acc.x * inv; o.y = acc.y * inv; o.z = acc.z * inv; o.w = acc.w * inv;
    *(float4*)&O[(size_t)(b * NQL + n0 + tx) * DDIM + v0 + ty * 4] = o;
}

// ---------------------------------------------------------------------------
extern "C" void kernel_launch(void* const* d_in, const int* in_sizes, int n_in,
                              void* d_out, int out_size, void* d_ws, size_t ws_size,
                              hipStream_t stream)
{
    const float* query = (const float*)d_in[0]; // (4,512,256)
    const float* key   = (const float*)d_in[1]; // (4,512,256)
    const float* value = (const float*)d_in[2]; // (4,512,256)
    const float* Wq    = (const float*)d_in[3]; // (256,256)
    const float* Wk    = (const float*)d_in[4]; // (256,256)
    const float* Wv    = (const float*)d_in[5]; // (256,)
    float* out = (float*)d_out;                 // (4,512,256)

    // workspace layout (fp32): EqT 2MB | EkT 2MB | P 4MB
    float* EqT = (float*)d_ws;                        // [4][256][512]
    float* EkT = EqT + (size_t)NB * HDIM * NQL;       // [4][256][512]
    float* P   = EkT + (size_t)NB * HDIM * ML;        // [4][512][512]  (= e^S)

    dim3 gProj(NQL / 32, HDIM / 64, NB * 2);
    proj_kernel<<<gProj, 256, 0, stream>>>(query, key, Wq, Wk, EqT, EkT);

    dim3 gSc(ML / 64, NQL / 32, NB);
    scores_kernel<<<gSc, 256, 0, stream>>>(EqT, EkT, Wv, P);

    dim3 gSav(DDIM / 64, NQL / 16, NB);
    sav_kernel<<<gSav, 256, 0, stream>>>(P, value, out);
}